// Round 2
// baseline (1060.099 us; speedup 1.0000x reference)
//
#include <hip/hip_runtime.h>
#include <hip/hip_bf16.h>

// Problem constants (MoD block: B=4, T=4096, D=2048, H=16, HD=128, K=512, DFF=5461)
#define BB 4
#define TT 4096
#define DD 2048
#define HH 16
#define HDD 128
#define KSEL 512
#define DFF 5461
#define DFFP 5504   // padded to multiple of 128

typedef __attribute__((ext_vector_type(8))) short short8;
typedef __attribute__((ext_vector_type(4))) float floatx4;

// ---------------------------------------------------------------- async 16B global->LDS
__device__ __forceinline__ void g2l16(const void* g, void* l) {
  __builtin_amdgcn_global_load_lds((const __attribute__((address_space(1))) void*)g,
                                   (__attribute__((address_space(3))) void*)l,
                                   16, 0, 0);
}

// ---------------------------------------------------------------- router + passthrough copy
__global__ __launch_bounds__(256) void router_copy(
    const float* __restrict__ x, const float* __restrict__ rw,
    float* __restrict__ out, float* __restrict__ scores) {
  const long row = blockIdx.x;              // B*T rows
  const long base = row * DD;
  const int tid = threadIdx.x;
  float s = 0.f;
#pragma unroll
  for (int it = 0; it < 2; ++it) {
    const int c = (tid + it * 256) * 4;
    const float4 v = *(const float4*)(x + base + c);
    *(float4*)(out + base + c) = v;
    const float4 w = *(const float4*)(rw + c);
    s += v.x * w.x + v.y * w.y + v.z * w.z + v.w * w.w;
  }
  __shared__ float red[256];
  red[tid] = s; __syncthreads();
  for (int st = 128; st > 0; st >>= 1) { if (tid < st) red[tid] += red[tid + st]; __syncthreads(); }
  if (tid == 0) scores[row] = red[0];
}

// ---------------------------------------------------------------- exact top-K (per batch), sorted ascending
__global__ __launch_bounds__(256) void topk_select(
    const float* __restrict__ scores, int* __restrict__ idx_sel) {
  const int b = blockIdx.x;
  const int tid = threadIdx.x;
  __shared__ float key[TT];
  __shared__ float fred[256];
  __shared__ int ired[256];
  __shared__ int ia[256], ib[256];
  __shared__ float s_lo, s_hi;
  __shared__ int s_strict;
  const float* sc = scores + (long)b * TT;
  for (int t = tid; t < TT; t += 256) key[t] = sc[t] + (float)t * 1e-6f;
  __syncthreads();
  float mn = 1e30f, mx = -1e30f;
  for (int t = tid; t < TT; t += 256) { const float v = key[t]; mn = fminf(mn, v); mx = fmaxf(mx, v); }
  fred[tid] = mn; __syncthreads();
  for (int s = 128; s > 0; s >>= 1) { if (tid < s) fred[tid] = fminf(fred[tid], fred[tid + s]); __syncthreads(); }
  if (tid == 0) s_lo = fred[0] - 1.f;
  __syncthreads();
  fred[tid] = mx; __syncthreads();
  for (int s = 128; s > 0; s >>= 1) { if (tid < s) fred[tid] = fmaxf(fred[tid], fred[tid + s]); __syncthreads(); }
  if (tid == 0) s_hi = fred[0];
  __syncthreads();
  // bisection: invariant cnt(>lo) >= K, cnt(>hi) < K
  for (int it = 0; it < 64; ++it) {
    const float lo = s_lo, hi = s_hi;
    const float mid = 0.5f * (lo + hi);
    if (!(mid > lo && mid < hi)) break;  // uniform across block
    int c = 0;
    for (int t = tid; t < TT; t += 256) c += (key[t] > mid) ? 1 : 0;
    ired[tid] = c; __syncthreads();
    for (int s = 128; s > 0; s >>= 1) { if (tid < s) ired[tid] += ired[tid + s]; __syncthreads(); }
    if (tid == 0) { if (ired[0] >= KSEL) s_lo = mid; else s_hi = mid; }
    __syncthreads();
  }
  const float hi = s_hi;
  const int t0c = tid * 16;
  int cs = 0, ce = 0;
  for (int t = t0c; t < t0c + 16; ++t) { const float v = key[t]; cs += (v > hi); ce += (v == hi); }
  ia[tid] = cs; ib[tid] = ce; __syncthreads();
  if (tid == 0) {
    int st = 0, et = 0;
    for (int i2 = 0; i2 < 256; ++i2) { const int a = ia[i2], e2 = ib[i2]; ia[i2] = st; ib[i2] = et; st += a; et += e2; }
    s_strict = st;
  }
  __syncthreads();
  const int neq = KSEL - s_strict;  // how many ==hi keys to take (smallest t first; stable top_k)
  {
    int eqr = ib[tid];
    int sel = 0;
    for (int t = t0c; t < t0c + 16; ++t) {
      const float v = key[t];
      if (v > hi) sel++;
      else if (v == hi) { if (eqr < neq) sel++; eqr++; }
    }
    ired[tid] = sel;
  }
  __syncthreads();
  if (tid == 0) { int st = 0; for (int i2 = 0; i2 < 256; ++i2) { const int a = ired[i2]; ired[i2] = st; st += a; } }
  __syncthreads();
  {
    int pos = ired[tid];
    int eqr = ib[tid];
    for (int t = t0c; t < t0c + 16; ++t) {
      const float v = key[t];
      bool s = false;
      if (v > hi) s = true;
      else if (v == hi) { s = (eqr < neq); eqr++; }
      if (s) idx_sel[(long)b * KSEL + (pos++)] = t;
    }
  }
}

// ---------------------------------------------------------------- (optional gather) + RMSNorm -> bf16
__global__ __launch_bounds__(256) void rmsnorm_rows(
    const float* __restrict__ src, const int* __restrict__ idx,
    const float* __restrict__ w, __hip_bfloat16* __restrict__ dst, int gather) {
  const int m = blockIdx.x;  // 0..B*KSEL-1
  const int tid = threadIdx.x;
  const float* row;
  if (gather) {
    const int b = m >> 9;
    const int t = idx[m];
    row = src + ((long)b * TT + t) * DD;
  } else {
    row = src + (long)m * DD;
  }
  const float4 v0 = *(const float4*)(row + tid * 4);
  const float4 v1 = *(const float4*)(row + 1024 + tid * 4);
  float ss = v0.x * v0.x + v0.y * v0.y + v0.z * v0.z + v0.w * v0.w
           + v1.x * v1.x + v1.y * v1.y + v1.z * v1.z + v1.w * v1.w;
  __shared__ float red[256];
  __shared__ float s_r;
  red[tid] = ss; __syncthreads();
  for (int s = 128; s > 0; s >>= 1) { if (tid < s) red[tid] += red[tid + s]; __syncthreads(); }
  if (tid == 0) s_r = rsqrtf(red[0] * (1.f / (float)DD) + 1e-6f);
  __syncthreads();
  const float r = s_r;
  const float4 w0 = *(const float4*)(w + tid * 4);
  const float4 w1v = *(const float4*)(w + 1024 + tid * 4);
  __hip_bfloat16* drow = dst + (long)m * DD;
  const int c = tid * 4;
  drow[c + 0] = __float2bfloat16(v0.x * r * w0.x);
  drow[c + 1] = __float2bfloat16(v0.y * r * w0.y);
  drow[c + 2] = __float2bfloat16(v0.z * r * w0.z);
  drow[c + 3] = __float2bfloat16(v0.w * r * w0.w);
  drow[1024 + c + 0] = __float2bfloat16(v1.x * r * w1v.x);
  drow[1024 + c + 1] = __float2bfloat16(v1.y * r * w1v.y);
  drow[1024 + c + 2] = __float2bfloat16(v1.z * r * w1v.z);
  drow[1024 + c + 3] = __float2bfloat16(v1.w * r * w1v.w);
}

// ---------------------------------------------------------------- transpose + fp32->bf16 (zero-pad)
__global__ __launch_bounds__(256) void transpose_cast(
    const float* __restrict__ in, __hip_bfloat16* __restrict__ out,
    int R, int C, int Rp, int Cp) {
  __shared__ float tile[32][33];
  const int r0 = blockIdx.x * 32, c0 = blockIdx.y * 32;
  const int tx = threadIdx.x & 31, ty = threadIdx.x >> 5;
  for (int yy = ty; yy < 32; yy += 8) {
    const int r = r0 + yy, c = c0 + tx;
    tile[yy][tx] = (r < R && c < C) ? in[(long)r * C + c] : 0.f;
  }
  __syncthreads();
  for (int yy = ty; yy < 32; yy += 8) {
    const int c = c0 + yy, r = r0 + tx;
    if (c < Cp && r < Rp) out[(long)c * Rp + r] = __float2bfloat16(tile[tx][yy]);
  }
}

// ---------------------------------------------------------------- causal softmax, one wave per row
__global__ __launch_bounds__(256) void softmax_rows(
    const __hip_bfloat16* __restrict__ S, __hip_bfloat16* __restrict__ P) {
  const int row = blockIdx.x * 4 + (threadIdx.x >> 6);   // B*H*512 rows
  const int lane = threadIdx.x & 63;
  const int i = row & (KSEL - 1);
  const long base = (long)row * KSEL;
  float v[8];
  float mx = -1e30f;
#pragma unroll
  for (int e = 0; e < 8; ++e) {
    const int j = e * 64 + lane;
    const float s = (j <= i) ? __bfloat162float(S[base + j]) : -1e30f;
    v[e] = s; mx = fmaxf(mx, s);
  }
#pragma unroll
  for (int d = 32; d > 0; d >>= 1) mx = fmaxf(mx, __shfl_xor(mx, d, 64));
  float sum = 0.f;
#pragma unroll
  for (int e = 0; e < 8; ++e) { const float p = __expf(v[e] - mx); v[e] = p; sum += p; }
#pragma unroll
  for (int d = 32; d > 0; d >>= 1) sum += __shfl_xor(sum, d, 64);
  const float inv = 1.f / sum;
#pragma unroll
  for (int e = 0; e < 8; ++e) P[base + e * 64 + lane] = __float2bfloat16(v[e] * inv);
}

// ---------------------------------------------------------------- GEMM: C(MxN) = A(MxK) * Bt(NxK)^T, m97 structure
// XCD-partitioned swizzle (gmx>0): xcd = blockIdx.x&7 owns a private (bm,bn)
// rectangle so each per-XCD L2 only fetches its own A/B stripes.
// EPI: 0 = S write (bf16, scaled, batched z)         1 = QKV scatter to q/k/v^T
//      2 = out-proj: x1 = acc + gather(x)   (fp32)   3 = dual-B FFN: u = silu(acc1)*acc2 (bf16)
//      4 = final: d_out[scatter] = x1 + acc (fp32)   5 = PV -> o (bf16, (b,h) decompose)
template <int EPI>
__global__ __launch_bounds__(256) void gemm_bt(
    const __hip_bfloat16* __restrict__ A,
    const __hip_bfloat16* __restrict__ B,
    const __hip_bfloat16* __restrict__ B2,
    int ntm, int ntn, int gmx, int gnx,
    int K, long bsA, long bsB, float scale,
    void* __restrict__ out0,
    const int* __restrict__ idx,
    const float* __restrict__ xres,
    __hip_bfloat16* __restrict__ qb,
    __hip_bfloat16* __restrict__ kb,
    __hip_bfloat16* __restrict__ vtb) {
  constexpr bool DUAL = (EPI == 3);
  __shared__ unsigned short As[128 * 32];
  __shared__ unsigned short Bs[128 * 32];
  __shared__ unsigned short Bs2[DUAL ? 128 * 32 : 8];

  const int z = blockIdx.z;
  int bm, bn;
  if (gmx > 0) {
    const int xcd = blockIdx.x & 7;
    const int j = blockIdx.x >> 3;
    const int xm = xcd % gmx, xn = xcd / gmx;
    const int m_lo = (xm * ntm) / gmx;
    const int m_cnt = ((xm + 1) * ntm) / gmx - m_lo;
    const int n_lo = (xn * ntn) / gnx;
    const int n_cnt = ((xn + 1) * ntn) / gnx - n_lo;
    if (j >= m_cnt * n_cnt) return;   // uniform exit (pre-LDS)
    bm = m_lo + j % m_cnt;
    bn = n_lo + j / m_cnt;
  } else {
    bm = blockIdx.x / ntn;
    bn = blockIdx.x % ntn;
  }
  const int tid = threadIdx.x;

  const __hip_bfloat16* Ab = A + (long)z * bsA + (long)bm * 128 * K;
  const __hip_bfloat16* Bb = B + (long)z * bsB + (long)bn * 128 * K;

  const int m1 = tid >> 2;          // staging row (0..63), +64 for second chunk
  const int p8 = (tid & 3) * 8;     // staging col offset in elements

  const floatx4 zero4 = {0.f, 0.f, 0.f, 0.f};
  floatx4 acc[4][4];
  floatx4 acc2[4][4];
#pragma unroll
  for (int i = 0; i < 4; ++i)
#pragma unroll
    for (int j = 0; j < 4; ++j) { acc[i][j] = zero4; if constexpr (DUAL) acc2[i][j] = zero4; }

  const int lane = tid & 63;
  const int wave = tid >> 6;
  const int wm = (wave & 1) << 6;
  const int wn = (wave >> 1) << 6;
  const int lrow = lane & 15;
  const int kq = (lane >> 4) << 3;

  for (int k0 = 0; k0 < K; k0 += 32) {
    const __hip_bfloat16* ag = Ab + (long)m1 * K + (k0 + p8);
    g2l16(ag, &As[tid * 8]);
    g2l16(ag + (long)64 * K, &As[(tid + 256) * 8]);
    const __hip_bfloat16* bg = Bb + (long)m1 * K + (k0 + p8);
    g2l16(bg, &Bs[tid * 8]);
    g2l16(bg + (long)64 * K, &Bs[(tid + 256) * 8]);
    if constexpr (DUAL) {
      const __hip_bfloat16* b2g = B2 + (long)bn * 128 * K + (long)m1 * K + (k0 + p8);
      g2l16(b2g, &Bs2[tid * 8]);
      g2l16(b2g + (long)64 * K, &Bs2[(tid + 256) * 8]);
    }
    __syncthreads();
    short8 af[4], bfr[4];
#pragma unroll
    for (int i = 0; i < 4; ++i) af[i] = *(const short8*)&As[(wm + i * 16 + lrow) * 32 + kq];
#pragma unroll
    for (int j = 0; j < 4; ++j) bfr[j] = *(const short8*)&Bs[(wn + j * 16 + lrow) * 32 + kq];
#pragma unroll
    for (int i = 0; i < 4; ++i)
#pragma unroll
      for (int j = 0; j < 4; ++j)
        acc[i][j] = __builtin_amdgcn_mfma_f32_16x16x32_bf16(af[i], bfr[j], acc[i][j], 0, 0, 0);
    if constexpr (DUAL) {
      short8 bf2[4];
#pragma unroll
      for (int j = 0; j < 4; ++j) bf2[j] = *(const short8*)&Bs2[(wn + j * 16 + lrow) * 32 + kq];
#pragma unroll
      for (int i = 0; i < 4; ++i)
#pragma unroll
        for (int j = 0; j < 4; ++j)
          acc2[i][j] = __builtin_amdgcn_mfma_f32_16x16x32_bf16(af[i], bf2[j], acc2[i][j], 0, 0, 0);
    }
    __syncthreads();
  }

  // C/D layout (16x16x32): col = lane&15, row = (lane>>4)*4 + reg  [m89-verified]
  const int cn = lane & 15;
  const int rb = (lane >> 4) << 2;
#pragma unroll
  for (int i = 0; i < 4; ++i) {
#pragma unroll
    for (int j = 0; j < 4; ++j) {
#pragma unroll
      for (int r = 0; r < 4; ++r) {
        const int gm = bm * 128 + wm + i * 16 + rb + r;
        const int gn = bn * 128 + wn + j * 16 + cn;
        const float v = acc[i][j][r];
        if constexpr (EPI == 0) {
          ((__hip_bfloat16*)out0)[(long)z * KSEL * KSEL + (long)gm * KSEL + gn] =
              __float2bfloat16(v * scale);
        } else if constexpr (EPI == 5) {
          const int b = z >> 4, h = z & 15;
          ((__hip_bfloat16*)out0)[((long)(b * KSEL + gm)) * DD + h * HDD + gn] =
              __float2bfloat16(v);
        } else if constexpr (EPI == 1) {
          const int b = gm >> 9, t = gm & 511;
          const int sec = gn >> 11, rem = gn & 2047, h = rem >> 7, hd = rem & 127;
          const __hip_bfloat16 val = __float2bfloat16(v);
          const long bh = (long)b * HH + h;
          if (sec == 0)      qb[(bh * KSEL + t) * HDD + hd] = val;
          else if (sec == 1) kb[(bh * KSEL + t) * HDD + hd] = val;
          else               vtb[(bh * HDD + hd) * KSEL + t] = val;
        } else if constexpr (EPI == 2) {
          const int b = gm >> 9;
          const int t0 = idx[gm];
          ((float*)out0)[(long)gm * DD + gn] = xres[((long)b * TT + t0) * DD + gn] + v;
        } else if constexpr (EPI == 3) {
          const float a1 = v;
          const float a2 = acc2[i][j][r];
          const float sgl = a1 / (1.f + __expf(-a1));
          ((__hip_bfloat16*)out0)[(long)gm * DFFP + gn] = __float2bfloat16(sgl * a2);
        } else if constexpr (EPI == 4) {
          const int b = gm >> 9;
          const int t0 = idx[gm];
          ((float*)out0)[((long)b * TT + t0) * DD + gn] = xres[(long)gm * DD + gn] + v;
        }
      }
    }
  }
}

// ================================================================ host
extern "C" void kernel_launch(void* const* d_in, const int* in_sizes, int n_in,
                              void* d_out, int out_size, void* d_ws, size_t ws_size,
                              hipStream_t stream) {
  const float* x        = (const float*)d_in[0];
  // d_in[1] = position_ids (arange; causal mask reduces to index order on sorted selection)
  const float* router_w = (const float*)d_in[2];
  const float* norm1_w  = (const float*)d_in[3];
  const float* qkv_w    = (const float*)d_in[4];
  const float* out_w    = (const float*)d_in[5];
  const float* norm2_w  = (const float*)d_in[6];
  const float* w1       = (const float*)d_in[7];
  const float* w2       = (const float*)d_in[8];
  const float* w3       = (const float*)d_in[9];
  float* out = (float*)d_out;

  char* wsb = (char*)d_ws;
  size_t off = 0;
  auto alloc = [&](size_t bytes) -> void* {
    void* p = wsb + off;
    off += (bytes + 255) & ~(size_t)255;
    return p;
  };
  float* scores = (float*)alloc((size_t)BB * TT * 4);
  int* idxs     = (int*)alloc((size_t)BB * KSEL * 4);
  __hip_bfloat16* qkvt = (__hip_bfloat16*)alloc((size_t)3 * DD * DD * 2);
  __hip_bfloat16* outt = (__hip_bfloat16*)alloc((size_t)DD * DD * 2);
  __hip_bfloat16* w1t  = (__hip_bfloat16*)alloc((size_t)DFFP * DD * 2);
  __hip_bfloat16* w2t  = (__hip_bfloat16*)alloc((size_t)DFFP * DD * 2);
  __hip_bfloat16* w3t  = (__hip_bfloat16*)alloc((size_t)DD * DFFP * 2);
  __hip_bfloat16* h1   = (__hip_bfloat16*)alloc((size_t)BB * KSEL * DD * 2);
  __hip_bfloat16* qbuf = (__hip_bfloat16*)alloc((size_t)BB * HH * KSEL * HDD * 2);
  __hip_bfloat16* kbuf = (__hip_bfloat16*)alloc((size_t)BB * HH * KSEL * HDD * 2);
  __hip_bfloat16* vtb  = (__hip_bfloat16*)alloc((size_t)BB * HH * KSEL * HDD * 2);
  __hip_bfloat16* Sbuf = (__hip_bfloat16*)alloc((size_t)BB * HH * KSEL * KSEL * 2);
  __hip_bfloat16* Pbuf = (__hip_bfloat16*)alloc((size_t)BB * HH * KSEL * KSEL * 2);
  // aliases (dead-buffer reuse; total ws ~193 MiB)
  __hip_bfloat16* obuf = h1;            // o reuses h1 (h1 dead after QKV GEMM)
  __hip_bfloat16* h2   = qbuf;          // h2 reuses q (q dead after S GEMM)
  __hip_bfloat16* ubuf = Pbuf;          // u (2048x5504 bf16) reuses P (dead after PV)
  float* x1f           = (float*)Sbuf;  // x1 (2048x2048 f32) reuses S (dead after softmax)
  (void)ws_size; (void)in_sizes; (void)n_in; (void)out_size;

  const float inv_sqrt_hd = 0.08838834764831845f;  // 1/sqrt(128)

  // 1. router scores + passthrough copy
  router_copy<<<dim3(BB * TT), dim3(256), 0, stream>>>(x, router_w, out, scores);
  // 2. exact top-K (sorted ascending)
  topk_select<<<dim3(BB), dim3(256), 0, stream>>>(scores, idxs);
  // 3. gather + rmsnorm1 -> h1 (bf16)
  rmsnorm_rows<<<dim3(BB * KSEL), dim3(256), 0, stream>>>(x, idxs, norm1_w, h1, 1);
  // 4. weight transposes (fp32 -> bf16, k-major)
  transpose_cast<<<dim3(DD / 32, 3 * DD / 32), dim3(256), 0, stream>>>(qkv_w, qkvt, DD, 3 * DD, DD, 3 * DD);
  transpose_cast<<<dim3(DD / 32, DD / 32), dim3(256), 0, stream>>>(out_w, outt, DD, DD, DD, DD);
  transpose_cast<<<dim3(DD / 32, DFFP / 32), dim3(256), 0, stream>>>(w1, w1t, DD, DFF, DD, DFFP);
  transpose_cast<<<dim3(DD / 32, DFFP / 32), dim3(256), 0, stream>>>(w2, w2t, DD, DFF, DD, DFFP);
  transpose_cast<<<dim3(DFFP / 32, DD / 32), dim3(256), 0, stream>>>(w3, w3t, DFF, DD, DFFP, DD);
  // 5. QKV GEMM: (2048 x 2048) @ (2048 x 6144), XCD-swizzled (2x4), rect 8x12=96 -> grid 768
  gemm_bt<1><<<dim3(8 * 96, 1, 1), dim3(256), 0, stream>>>(
      h1, qkvt, nullptr, 16, 48, 2, 4, DD, 0, 0, 1.f, nullptr, nullptr, nullptr, qbuf, kbuf, vtb);
  // 6. S = Q K^T / sqrt(HD), batched over (b,h) (legacy mapping)
  gemm_bt<0><<<dim3(4 * 4, 1, BB * HH), dim3(256), 0, stream>>>(
      qbuf, kbuf, nullptr, 4, 4, 0, 0, HDD, (long)KSEL * HDD, (long)KSEL * HDD, inv_sqrt_hd,
      Sbuf, nullptr, nullptr, nullptr, nullptr, nullptr);
  // 7. causal softmax -> P (bf16)
  softmax_rows<<<dim3(BB * HH * KSEL / 4), dim3(256), 0, stream>>>(Sbuf, Pbuf);
  // 8. O = P V, batched -> o rows (b*512+t) x 2048 (legacy mapping)
  gemm_bt<5><<<dim3(4, 1, BB * HH), dim3(256), 0, stream>>>(
      Pbuf, vtb, nullptr, 4, 1, 0, 0, KSEL, (long)KSEL * KSEL, (long)HDD * KSEL, 1.f,
      obuf, nullptr, nullptr, nullptr, nullptr, nullptr);
  // 9. out-proj + residual gather, XCD-swizzled (2x4), rect 8x4=32 -> grid 256
  gemm_bt<2><<<dim3(8 * 32, 1, 1), dim3(256), 0, stream>>>(
      obuf, outt, nullptr, 16, 16, 2, 4, DD, 0, 0, 1.f, x1f, idxs, x, nullptr, nullptr, nullptr);
  // 10. rmsnorm2 -> h2 (bf16)
  rmsnorm_rows<<<dim3(BB * KSEL), dim3(256), 0, stream>>>(x1f, nullptr, norm2_w, h2, 0);
  // 11. FFN dual GEMM, XCD-swizzled (2x4), rect max 8x11=88 -> grid 704
  gemm_bt<3><<<dim3(8 * 88, 1, 1), dim3(256), 0, stream>>>(
      h2, w1t, w2t, 16, 43, 2, 4, DD, 0, 0, 1.f, ubuf, nullptr, nullptr, nullptr, nullptr, nullptr);
  // 12. final GEMM + residual + scatter, XCD-swizzled (2x4), rect 8x4=32 -> grid 256
  gemm_bt<4><<<dim3(8 * 32, 1, 1), dim3(256), 0, stream>>>(
      ubuf, w3t, nullptr, 16, 16, 2, 4, DFFP, 0, 0, 1.f, out, idxs, x1f, nullptr, nullptr, nullptr);
}

// Round 3
// 919.996 us; speedup vs baseline: 1.1523x; 1.1523x over previous
//
#include <hip/hip_runtime.h>
#include <hip/hip_bf16.h>

// Problem constants (MoD block: B=4, T=4096, D=2048, H=16, HD=128, K=512, DFF=5461)
#define BB 4
#define TT 4096
#define DD 2048
#define HH 16
#define HDD 128
#define KSEL 512
#define DFF 5461
#define DFFP 5504   // padded to multiple of 128

typedef __attribute__((ext_vector_type(8))) short short8;
typedef __attribute__((ext_vector_type(4))) float floatx4;

// ---------------------------------------------------------------- async 16B global->LDS
__device__ __forceinline__ void g2l16(const void* g, void* l) {
  __builtin_amdgcn_global_load_lds((const __attribute__((address_space(1))) void*)g,
                                   (__attribute__((address_space(3))) void*)l,
                                   16, 0, 0);
}

// ---------------------------------------------------------------- router + passthrough copy
__global__ __launch_bounds__(256) void router_copy(
    const float* __restrict__ x, const float* __restrict__ rw,
    float* __restrict__ out, float* __restrict__ scores) {
  const long row = blockIdx.x;              // B*T rows
  const long base = row * DD;
  const int tid = threadIdx.x;
  float s = 0.f;
#pragma unroll
  for (int it = 0; it < 2; ++it) {
    const int c = (tid + it * 256) * 4;
    const float4 v = *(const float4*)(x + base + c);
    *(float4*)(out + base + c) = v;
    const float4 w = *(const float4*)(rw + c);
    s += v.x * w.x + v.y * w.y + v.z * w.z + v.w * w.w;
  }
  __shared__ float red[256];
  red[tid] = s; __syncthreads();
  for (int st = 128; st > 0; st >>= 1) { if (tid < st) red[tid] += red[tid + st]; __syncthreads(); }
  if (tid == 0) scores[row] = red[0];
}

// ---------------------------------------------------------------- exact top-K (per batch), sorted ascending
// Keys live in registers; bisection count via shfl-reduce (no LDS rereads).
__global__ __launch_bounds__(256) void topk_select(
    const float* __restrict__ scores, int* __restrict__ idx_sel) {
  const int b = blockIdx.x;
  const int tid = threadIdx.x;
  const int wave = tid >> 6, lane = tid & 63;
  const float* sc = scores + (long)b * TT;
  const int t0c = tid * 16;
  float v[16];
#pragma unroll
  for (int e = 0; e < 16; ++e) v[e] = sc[t0c + e] + (float)(t0c + e) * 1e-6f;

  __shared__ float smn[4], smx[4];
  __shared__ int scnt[4];
  __shared__ float s_lo, s_hi;
  __shared__ int s_strict;
  __shared__ int ia[256], ib[256], ired[256];

  float mn = v[0], mx = v[0];
#pragma unroll
  for (int e = 1; e < 16; ++e) { mn = fminf(mn, v[e]); mx = fmaxf(mx, v[e]); }
#pragma unroll
  for (int d = 32; d > 0; d >>= 1) { mn = fminf(mn, __shfl_xor(mn, d, 64)); mx = fmaxf(mx, __shfl_xor(mx, d, 64)); }
  if (lane == 0) { smn[wave] = mn; smx[wave] = mx; }
  __syncthreads();
  if (tid == 0) {
    s_lo = fminf(fminf(smn[0], smn[1]), fminf(smn[2], smn[3])) - 1.f;
    s_hi = fmaxf(fmaxf(smx[0], smx[1]), fmaxf(smx[2], smx[3]));
  }
  __syncthreads();
  // bisection: invariant cnt(>lo) >= K, cnt(>hi) < K
  for (int it = 0; it < 64; ++it) {
    const float lo = s_lo, hi = s_hi;
    const float mid = 0.5f * (lo + hi);
    if (!(mid > lo && mid < hi)) break;  // uniform
    int c = 0;
#pragma unroll
    for (int e = 0; e < 16; ++e) c += (v[e] > mid) ? 1 : 0;
#pragma unroll
    for (int d = 32; d > 0; d >>= 1) c += __shfl_xor(c, d, 64);
    if (lane == 0) scnt[wave] = c;
    __syncthreads();
    if (tid == 0) {
      const int tot = scnt[0] + scnt[1] + scnt[2] + scnt[3];
      if (tot >= KSEL) s_lo = mid; else s_hi = mid;
    }
    __syncthreads();
  }
  const float hi = s_hi;
  int cs = 0, ce = 0;
#pragma unroll
  for (int e = 0; e < 16; ++e) { cs += (v[e] > hi); ce += (v[e] == hi); }
  ia[tid] = cs; ib[tid] = ce; __syncthreads();
  if (tid == 0) {
    int st = 0, et = 0;
    for (int i2 = 0; i2 < 256; ++i2) { const int a = ia[i2], e2 = ib[i2]; ia[i2] = st; ib[i2] = et; st += a; et += e2; }
    s_strict = st;
  }
  __syncthreads();
  const int neq = KSEL - s_strict;  // how many ==hi keys to take (smallest t first; stable top_k)
  {
    int eqr = ib[tid];
    int sel = 0;
#pragma unroll
    for (int e = 0; e < 16; ++e) {
      if (v[e] > hi) sel++;
      else if (v[e] == hi) { if (eqr < neq) sel++; eqr++; }
    }
    ired[tid] = sel;
  }
  __syncthreads();
  if (tid == 0) { int st = 0; for (int i2 = 0; i2 < 256; ++i2) { const int a = ired[i2]; ired[i2] = st; st += a; } }
  __syncthreads();
  {
    int pos = ired[tid];
    int eqr = ib[tid];
#pragma unroll
    for (int e = 0; e < 16; ++e) {
      bool s = false;
      if (v[e] > hi) s = true;
      else if (v[e] == hi) { s = (eqr < neq); eqr++; }
      if (s) idx_sel[(long)b * KSEL + (pos++)] = t0c + e;
    }
  }
}

// ---------------------------------------------------------------- (optional gather) + RMSNorm -> bf16
__global__ __launch_bounds__(256) void rmsnorm_rows(
    const float* __restrict__ src, const int* __restrict__ idx,
    const float* __restrict__ w, __hip_bfloat16* __restrict__ dst, int gather) {
  const int m = blockIdx.x;  // 0..B*KSEL-1
  const int tid = threadIdx.x;
  const float* row;
  if (gather) {
    const int b = m >> 9;
    const int t = idx[m];
    row = src + ((long)b * TT + t) * DD;
  } else {
    row = src + (long)m * DD;
  }
  const float4 v0 = *(const float4*)(row + tid * 4);
  const float4 v1 = *(const float4*)(row + 1024 + tid * 4);
  float ss = v0.x * v0.x + v0.y * v0.y + v0.z * v0.z + v0.w * v0.w
           + v1.x * v1.x + v1.y * v1.y + v1.z * v1.z + v1.w * v1.w;
  __shared__ float red[256];
  __shared__ float s_r;
  red[tid] = ss; __syncthreads();
  for (int s = 128; s > 0; s >>= 1) { if (tid < s) red[tid] += red[tid + s]; __syncthreads(); }
  if (tid == 0) s_r = rsqrtf(red[0] * (1.f / (float)DD) + 1e-6f);
  __syncthreads();
  const float r = s_r;
  const float4 w0 = *(const float4*)(w + tid * 4);
  const float4 w1v = *(const float4*)(w + 1024 + tid * 4);
  __hip_bfloat16* drow = dst + (long)m * DD;
  const int c = tid * 4;
  drow[c + 0] = __float2bfloat16(v0.x * r * w0.x);
  drow[c + 1] = __float2bfloat16(v0.y * r * w0.y);
  drow[c + 2] = __float2bfloat16(v0.z * r * w0.z);
  drow[c + 3] = __float2bfloat16(v0.w * r * w0.w);
  drow[1024 + c + 0] = __float2bfloat16(v1.x * r * w1v.x);
  drow[1024 + c + 1] = __float2bfloat16(v1.y * r * w1v.y);
  drow[1024 + c + 2] = __float2bfloat16(v1.z * r * w1v.z);
  drow[1024 + c + 3] = __float2bfloat16(v1.w * r * w1v.w);
}

// ---------------------------------------------------------------- transpose + fp32->bf16 (zero-pad)
__global__ __launch_bounds__(256) void transpose_cast(
    const float* __restrict__ in, __hip_bfloat16* __restrict__ out,
    int R, int C, int Rp, int Cp) {
  __shared__ float tile[32][33];
  const int r0 = blockIdx.x * 32, c0 = blockIdx.y * 32;
  const int tx = threadIdx.x & 31, ty = threadIdx.x >> 5;
  for (int yy = ty; yy < 32; yy += 8) {
    const int r = r0 + yy, c = c0 + tx;
    tile[yy][tx] = (r < R && c < C) ? in[(long)r * C + c] : 0.f;
  }
  __syncthreads();
  for (int yy = ty; yy < 32; yy += 8) {
    const int c = c0 + yy, r = r0 + tx;
    if (c < Cp && r < Rp) out[(long)c * Rp + r] = __float2bfloat16(tile[tx][yy]);
  }
}

// ---------------------------------------------------------------- causal softmax, one wave per row
__global__ __launch_bounds__(256) void softmax_rows(
    const __hip_bfloat16* __restrict__ S, __hip_bfloat16* __restrict__ P) {
  const int row = blockIdx.x * 4 + (threadIdx.x >> 6);   // B*H*512 rows
  const int lane = threadIdx.x & 63;
  const int i = row & (KSEL - 1);
  const long base = (long)row * KSEL;
  float v[8];
  float mx = -1e30f;
#pragma unroll
  for (int e = 0; e < 8; ++e) {
    const int j = e * 64 + lane;
    const float s = (j <= i) ? __bfloat162float(S[base + j]) : -1e30f;
    v[e] = s; mx = fmaxf(mx, s);
  }
#pragma unroll
  for (int d = 32; d > 0; d >>= 1) mx = fmaxf(mx, __shfl_xor(mx, d, 64));
  float sum = 0.f;
#pragma unroll
  for (int e = 0; e < 8; ++e) { const float p = __expf(v[e] - mx); v[e] = p; sum += p; }
#pragma unroll
  for (int d = 32; d > 0; d >>= 1) sum += __shfl_xor(sum, d, 64);
  const float inv = 1.f / sum;
#pragma unroll
  for (int e = 0; e < 8; ++e) P[base + e * 64 + lane] = __float2bfloat16(v[e] * inv);
}

// ---------------------------------------------------------------- GEMM: C(Mx N) = A(MxK) * Bt(NxK)^T
// Tile 128 x BN (BN = 128 or 64). BN=64 halves LDS+acc -> more blocks/CU (latency hiding).
// XCD-partitioned swizzle (gmx>0): xcd = blockIdx.x&7 owns a private (bm,bn) rectangle.
// EPI: 0 = S write (bf16, scaled, batched z)         1 = QKV scatter to q/k/v^T
//      2 = out-proj: x1 = acc + gather(x)   (fp32)   3 = dual-B FFN: u = silu(acc1)*acc2 (bf16)
//      4 = final: d_out[scatter] = x1 + acc (fp32)   5 = PV -> o (bf16, (b,h) decompose)
template <int EPI, int BN>
__global__ __launch_bounds__(256) void gemm_bt(
    const __hip_bfloat16* __restrict__ A,
    const __hip_bfloat16* __restrict__ B,
    const __hip_bfloat16* __restrict__ B2,
    int ntm, int ntn, int gmx, int gnx,
    int K, long bsA, long bsB, float scale,
    void* __restrict__ out0,
    const int* __restrict__ idx,
    const float* __restrict__ xres,
    __hip_bfloat16* __restrict__ qb,
    __hip_bfloat16* __restrict__ kb,
    __hip_bfloat16* __restrict__ vtb) {
  constexpr bool DUAL = (EPI == 3);
  constexpr int WN = (BN == 128) ? 64 : 32;   // per-wave N extent
  constexpr int NJ = WN / 16;                 // 4 or 2
  __shared__ unsigned short As[128 * 32];
  __shared__ unsigned short Bs[BN * 32];
  __shared__ unsigned short Bs2[DUAL ? BN * 32 : 8];

  const int z = blockIdx.z;
  int bm, bn;
  if (gmx > 0) {
    const int xcd = blockIdx.x & 7;
    const int j = blockIdx.x >> 3;
    const int xm = xcd % gmx, xn = xcd / gmx;
    const int m_lo = (xm * ntm) / gmx;
    const int m_cnt = ((xm + 1) * ntm) / gmx - m_lo;
    const int n_lo = (xn * ntn) / gnx;
    const int n_cnt = ((xn + 1) * ntn) / gnx - n_lo;
    if (j >= m_cnt * n_cnt) return;   // uniform exit (pre-barrier)
    bm = m_lo + j % m_cnt;
    bn = n_lo + j / m_cnt;
  } else {
    bm = blockIdx.x / ntn;
    bn = blockIdx.x % ntn;
  }
  const int tid = threadIdx.x;

  const __hip_bfloat16* Ab = A + (long)z * bsA + (long)bm * 128 * K;
  const __hip_bfloat16* Bb = B + (long)z * bsB + (long)bn * BN * K;

  const int m1 = tid >> 2;          // staging row (0..63)
  const int p8 = (tid & 3) * 8;     // staging col offset in elements

  const floatx4 zero4 = {0.f, 0.f, 0.f, 0.f};
  floatx4 acc[4][NJ];
  floatx4 acc2[DUAL ? 4 : 1][DUAL ? NJ : 1];
#pragma unroll
  for (int i = 0; i < 4; ++i)
#pragma unroll
    for (int j = 0; j < NJ; ++j) { acc[i][j] = zero4; if constexpr (DUAL) acc2[i][j] = zero4; }

  const int lane = tid & 63;
  const int wave = tid >> 6;
  const int wm = (wave & 1) << 6;
  const int wn = (wave >> 1) * WN;
  const int lrow = lane & 15;
  const int kq = (lane >> 4) << 3;

  for (int k0 = 0; k0 < K; k0 += 32) {
    const __hip_bfloat16* ag = Ab + (long)m1 * K + (k0 + p8);
    g2l16(ag, &As[tid * 8]);
    g2l16(ag + (long)64 * K, &As[(tid + 256) * 8]);
    const __hip_bfloat16* bg = Bb + (long)m1 * K + (k0 + p8);
    g2l16(bg, &Bs[tid * 8]);
    if constexpr (BN == 128) g2l16(bg + (long)64 * K, &Bs[(tid + 256) * 8]);
    if constexpr (DUAL) {
      const __hip_bfloat16* b2g = B2 + (long)bn * BN * K + (long)m1 * K + (k0 + p8);
      g2l16(b2g, &Bs2[tid * 8]);
      if constexpr (BN == 128) g2l16(b2g + (long)64 * K, &Bs2[(tid + 256) * 8]);
    }
    __syncthreads();
    short8 af[4], bfr[NJ];
#pragma unroll
    for (int i = 0; i < 4; ++i) af[i] = *(const short8*)&As[(wm + i * 16 + lrow) * 32 + kq];
#pragma unroll
    for (int j = 0; j < NJ; ++j) bfr[j] = *(const short8*)&Bs[(wn + j * 16 + lrow) * 32 + kq];
#pragma unroll
    for (int i = 0; i < 4; ++i)
#pragma unroll
      for (int j = 0; j < NJ; ++j)
        acc[i][j] = __builtin_amdgcn_mfma_f32_16x16x32_bf16(af[i], bfr[j], acc[i][j], 0, 0, 0);
    if constexpr (DUAL) {
      short8 bf2[NJ];
#pragma unroll
      for (int j = 0; j < NJ; ++j) bf2[j] = *(const short8*)&Bs2[(wn + j * 16 + lrow) * 32 + kq];
#pragma unroll
      for (int i = 0; i < 4; ++i)
#pragma unroll
        for (int j = 0; j < NJ; ++j)
          acc2[i][j] = __builtin_amdgcn_mfma_f32_16x16x32_bf16(af[i], bf2[j], acc2[i][j], 0, 0, 0);
    }
    __syncthreads();
  }

  // C/D layout (16x16x32): col = lane&15, row = (lane>>4)*4 + reg  [m89-verified]
  const int cn = lane & 15;
  const int rb = (lane >> 4) << 2;
#pragma unroll
  for (int i = 0; i < 4; ++i) {
#pragma unroll
    for (int j = 0; j < NJ; ++j) {
#pragma unroll
      for (int r = 0; r < 4; ++r) {
        const int gm = bm * 128 + wm + i * 16 + rb + r;
        const int gn = bn * BN + wn + j * 16 + cn;
        const float v = acc[i][j][r];
        if constexpr (EPI == 0) {
          ((__hip_bfloat16*)out0)[(long)z * KSEL * KSEL + (long)gm * KSEL + gn] =
              __float2bfloat16(v * scale);
        } else if constexpr (EPI == 5) {
          const int b = z >> 4, h = z & 15;
          ((__hip_bfloat16*)out0)[((long)(b * KSEL + gm)) * DD + h * HDD + gn] =
              __float2bfloat16(v);
        } else if constexpr (EPI == 1) {
          const int b = gm >> 9, t = gm & 511;
          const int sec = gn >> 11, rem = gn & 2047, h = rem >> 7, hd = rem & 127;
          const __hip_bfloat16 val = __float2bfloat16(v);
          const long bh = (long)b * HH + h;
          if (sec == 0)      qb[(bh * KSEL + t) * HDD + hd] = val;
          else if (sec == 1) kb[(bh * KSEL + t) * HDD + hd] = val;
          else               vtb[(bh * HDD + hd) * KSEL + t] = val;
        } else if constexpr (EPI == 2) {
          const int b = gm >> 9;
          const int t0 = idx[gm];
          ((float*)out0)[(long)gm * DD + gn] = xres[((long)b * TT + t0) * DD + gn] + v;
        } else if constexpr (EPI == 3) {
          const float a1 = v;
          const float a2 = acc2[i][j][r];
          const float sgl = a1 / (1.f + __expf(-a1));
          ((__hip_bfloat16*)out0)[(long)gm * DFFP + gn] = __float2bfloat16(sgl * a2);
        } else if constexpr (EPI == 4) {
          const int b = gm >> 9;
          const int t0 = idx[gm];
          ((float*)out0)[((long)b * TT + t0) * DD + gn] = xres[(long)gm * DD + gn] + v;
        }
      }
    }
  }
}

// ================================================================ host
extern "C" void kernel_launch(void* const* d_in, const int* in_sizes, int n_in,
                              void* d_out, int out_size, void* d_ws, size_t ws_size,
                              hipStream_t stream) {
  const float* x        = (const float*)d_in[0];
  // d_in[1] = position_ids (arange; causal mask reduces to index order on sorted selection)
  const float* router_w = (const float*)d_in[2];
  const float* norm1_w  = (const float*)d_in[3];
  const float* qkv_w    = (const float*)d_in[4];
  const float* out_w    = (const float*)d_in[5];
  const float* norm2_w  = (const float*)d_in[6];
  const float* w1       = (const float*)d_in[7];
  const float* w2       = (const float*)d_in[8];
  const float* w3       = (const float*)d_in[9];
  float* out = (float*)d_out;

  char* wsb = (char*)d_ws;
  size_t off = 0;
  auto alloc = [&](size_t bytes) -> void* {
    void* p = wsb + off;
    off += (bytes + 255) & ~(size_t)255;
    return p;
  };
  float* scores = (float*)alloc((size_t)BB * TT * 4);
  int* idxs     = (int*)alloc((size_t)BB * KSEL * 4);
  __hip_bfloat16* qkvt = (__hip_bfloat16*)alloc((size_t)3 * DD * DD * 2);
  __hip_bfloat16* outt = (__hip_bfloat16*)alloc((size_t)DD * DD * 2);
  __hip_bfloat16* w1t  = (__hip_bfloat16*)alloc((size_t)DFFP * DD * 2);
  __hip_bfloat16* w2t  = (__hip_bfloat16*)alloc((size_t)DFFP * DD * 2);
  __hip_bfloat16* w3t  = (__hip_bfloat16*)alloc((size_t)DD * DFFP * 2);
  __hip_bfloat16* h1   = (__hip_bfloat16*)alloc((size_t)BB * KSEL * DD * 2);
  __hip_bfloat16* qbuf = (__hip_bfloat16*)alloc((size_t)BB * HH * KSEL * HDD * 2);
  __hip_bfloat16* kbuf = (__hip_bfloat16*)alloc((size_t)BB * HH * KSEL * HDD * 2);
  __hip_bfloat16* vtb  = (__hip_bfloat16*)alloc((size_t)BB * HH * KSEL * HDD * 2);
  __hip_bfloat16* Sbuf = (__hip_bfloat16*)alloc((size_t)BB * HH * KSEL * KSEL * 2);
  __hip_bfloat16* Pbuf = (__hip_bfloat16*)alloc((size_t)BB * HH * KSEL * KSEL * 2);
  // aliases (dead-buffer reuse; total ws ~193 MiB)
  __hip_bfloat16* obuf = h1;            // o reuses h1 (h1 dead after QKV GEMM)
  __hip_bfloat16* h2   = qbuf;          // h2 reuses q (q dead after S GEMM)
  __hip_bfloat16* ubuf = Pbuf;          // u (2048x5504 bf16) reuses P (dead after PV)
  float* x1f           = (float*)Sbuf;  // x1 (2048x2048 f32) reuses S (dead after softmax)
  (void)ws_size; (void)in_sizes; (void)n_in; (void)out_size;

  const float inv_sqrt_hd = 0.08838834764831845f;  // 1/sqrt(128)

  // 1. router scores + passthrough copy
  router_copy<<<dim3(BB * TT), dim3(256), 0, stream>>>(x, router_w, out, scores);
  // 2. exact top-K (sorted ascending), register-resident bisection
  topk_select<<<dim3(BB), dim3(256), 0, stream>>>(scores, idxs);
  // 3. gather + rmsnorm1 -> h1 (bf16)
  rmsnorm_rows<<<dim3(BB * KSEL), dim3(256), 0, stream>>>(x, idxs, norm1_w, h1, 1);
  // 4. weight transposes (fp32 -> bf16, k-major)
  transpose_cast<<<dim3(DD / 32, 3 * DD / 32), dim3(256), 0, stream>>>(qkv_w, qkvt, DD, 3 * DD, DD, 3 * DD);
  transpose_cast<<<dim3(DD / 32, DD / 32), dim3(256), 0, stream>>>(out_w, outt, DD, DD, DD, DD);
  transpose_cast<<<dim3(DD / 32, DFFP / 32), dim3(256), 0, stream>>>(w1, w1t, DD, DFF, DD, DFFP);
  transpose_cast<<<dim3(DD / 32, DFFP / 32), dim3(256), 0, stream>>>(w2, w2t, DD, DFF, DD, DFFP);
  transpose_cast<<<dim3(DFFP / 32, DD / 32), dim3(256), 0, stream>>>(w3, w3t, DFF, DD, DFFP, DD);
  // 5. QKV GEMM: (2048x2048)@(2048x6144), tile 128x64, XCD 2x4, rect 8x24 -> grid 1536 (6/CU)
  gemm_bt<1, 64><<<dim3(8 * 192, 1, 1), dim3(256), 0, stream>>>(
      h1, qkvt, nullptr, 16, 96, 2, 4, DD, 0, 0, 1.f, nullptr, nullptr, nullptr, qbuf, kbuf, vtb);
  // 6. S = Q K^T / sqrt(HD), batched over (b,h), tile 128x128 (K=128 tiny)
  gemm_bt<0, 128><<<dim3(4 * 4, 1, BB * HH), dim3(256), 0, stream>>>(
      qbuf, kbuf, nullptr, 4, 4, 0, 0, HDD, (long)KSEL * HDD, (long)KSEL * HDD, inv_sqrt_hd,
      Sbuf, nullptr, nullptr, nullptr, nullptr, nullptr);
  // 7. causal softmax -> P (bf16)
  softmax_rows<<<dim3(BB * HH * KSEL / 4), dim3(256), 0, stream>>>(Sbuf, Pbuf);
  // 8. O = P V, batched, tile 128x64 -> grid 8 x 64 z = 512 (2/CU)
  gemm_bt<5, 64><<<dim3(8, 1, BB * HH), dim3(256), 0, stream>>>(
      Pbuf, vtb, nullptr, 4, 2, 0, 0, KSEL, (long)KSEL * KSEL, (long)HDD * KSEL, 1.f,
      obuf, nullptr, nullptr, nullptr, nullptr, nullptr);
  // 9. out-proj + residual gather, tile 128x64, XCD 2x4, rect 8x8 -> grid 512 (2/CU)
  gemm_bt<2, 64><<<dim3(8 * 64, 1, 1), dim3(256), 0, stream>>>(
      obuf, outt, nullptr, 16, 32, 2, 4, DD, 0, 0, 1.f, x1f, idxs, x, nullptr, nullptr, nullptr);
  // 10. rmsnorm2 -> h2 (bf16)
  rmsnorm_rows<<<dim3(BB * KSEL), dim3(256), 0, stream>>>(x1f, nullptr, norm2_w, h2, 0);
  // 11. FFN dual GEMM, tile 128x64, XCD 2x4, rect max 8x22=176 -> grid 1408 (5.5/CU)
  gemm_bt<3, 64><<<dim3(8 * 176, 1, 1), dim3(256), 0, stream>>>(
      h2, w1t, w2t, 16, 86, 2, 4, DD, 0, 0, 1.f, ubuf, nullptr, nullptr, nullptr, nullptr, nullptr);
  // 12. final GEMM + residual + scatter, tile 128x64, XCD 2x4, rect 8x8 -> grid 512 (2/CU)
  gemm_bt<4, 64><<<dim3(8 * 64, 1, 1), dim3(256), 0, stream>>>(
      ubuf, w3t, nullptr, 16, 32, 2, 4, DFFP, 0, 0, 1.f, out, idxs, x1f, nullptr, nullptr, nullptr);
}